// Round 6
// baseline (273.045 us; speedup 1.0000x reference)
//
#include <hip/hip_runtime.h>
#include <hip/hip_bf16.h>

typedef short bf16x8 __attribute__((ext_vector_type(8)));
typedef float f32x4 __attribute__((ext_vector_type(4)));
typedef float f32x2 __attribute__((ext_vector_type(2)));

#define BKT_SHIFT 9
#define BKT_RANGE 512          // nodes per bucket
#define MAXBKT 256             // N <= 131072 (src packs in 17 bits)

__device__ __forceinline__ float bf2f(unsigned short u){
  union { unsigned int i; float f; } v; v.i = ((unsigned int)u)<<16; return v.f;
}
__device__ __forceinline__ unsigned short f2bf(float f){
  union { float f; unsigned int i; } v; v.f = f;
  unsigned int i = v.i;
  return (unsigned short)((i + 0x7fffu + ((i>>16)&1u)) >> 16);  // RNE
}
// acc += unpack2(v) * m   (compiler packs to v_pk_fma_f32)
__device__ __forceinline__ void accfma(f32x2& a, unsigned int v, float m){
  union { unsigned int i; float f; } lo, hi;
  lo.i = v << 16; hi.i = v & 0xffff0000u;
  a[0] = fmaf(lo.f, m, a[0]);
  a[1] = fmaf(hi.f, m, a[1]);
}

// ---------------- bucket-sort CSR build ----------------
// B1: per-block LDS histogram of dst-buckets -> global bucket counts
__global__ void k_bcount(const int* dst, int* gcount, int ne, int nbk){
  __shared__ int cnt[MAXBKT];
  int tid = threadIdx.x;
  if(tid < nbk) cnt[tid] = 0;
  __syncthreads();
  int base = blockIdx.x * 4096;
#pragma unroll
  for(int i=0;i<16;++i){
    int e = base + i*256 + tid;
    if(e < ne) atomicAdd(&cnt[dst[e] >> BKT_SHIFT], 1);
  }
  __syncthreads();
  if(tid < nbk && cnt[tid] > 0) atomicAdd(&gcount[tid], cnt[tid]);
}

// B2: exclusive scan of bucket counts -> base & cursor
__global__ void k_bscan(const int* gcount, int* gbase, int* gcursor, int nbk){
  __shared__ int sm[256];
  int t = threadIdx.x;
  int v = (t<nbk) ? gcount[t] : 0;
  sm[t] = v;
  __syncthreads();
  for(int off=1; off<256; off<<=1){
    int a = (t>=off) ? sm[t-off] : 0;
    __syncthreads();
    sm[t] += a;
    __syncthreads();
  }
  if(t<nbk){
    int excl = sm[t] - v;
    gbase[t] = excl;
    gcursor[t] = excl;
  }
}

// B3: scatter packed (src | dloc<<17) into bucket-partitioned ebuf via LDS ranking
__global__ void k_bscatter(const int* src, const int* dst, int* gcursor,
                           unsigned int* ebuf, int ne, int nbk){
  __shared__ int cnt[MAXBKT];
  __shared__ int runbase[MAXBKT];
  int tid = threadIdx.x;
  if(tid < nbk) cnt[tid] = 0;
  __syncthreads();
  int base = blockIdx.x * 4096;
  int pk[16], bk[16], re[16];
#pragma unroll
  for(int i=0;i<16;++i){
    int e = base + i*256 + tid;
    if(e < ne){
      int d = dst[e];
      bk[i] = d >> BKT_SHIFT;
      pk[i] = (unsigned)src[e] | ((unsigned)(d & (BKT_RANGE-1)) << 17);
      re[i] = atomicAdd(&cnt[bk[i]], 1);
    } else bk[i] = -1;
  }
  __syncthreads();
  if(tid < nbk) runbase[tid] = cnt[tid] ? atomicAdd(&gcursor[tid], cnt[tid]) : 0;
  __syncthreads();
#pragma unroll
  for(int i=0;i<16;++i){
    if(bk[i] >= 0) ebuf[runbase[bk[i]] + re[i]] = pk[i];
  }
}

// B4: per-bucket counting sort -> csr + row_off. grid = nbk, block = 512.
__global__ void k_bsort(const unsigned int* ebuf, const int* gbase, const int* gcursor,
                        int* csr, int* row_off, int n, int ne, int nbk){
  __shared__ int h[BKT_RANGE];
  __shared__ int cur[BKT_RANGE];
  int t = threadIdx.x;
  int k = blockIdx.x;
  int lo = k << BKT_SHIFT;
  int beg = gbase[k], end = gcursor[k];
  h[t] = 0;
  __syncthreads();
  for(int e = beg + t; e < end; e += 512)
    atomicAdd(&h[ebuf[e] >> 17], 1);
  __syncthreads();
  int v = h[t];
  // inclusive scan over 512
  __shared__ int sm[512];
  sm[t] = v;
  __syncthreads();
  for(int off=1; off<512; off<<=1){
    int a = (t>=off) ? sm[t-off] : 0;
    __syncthreads();
    sm[t] += a;
    __syncthreads();
  }
  int excl = beg + sm[t] - v;
  cur[t] = excl;
  if(lo + t < n) row_off[lo + t] = excl;
  if(k == nbk-1 && t == 0) row_off[n] = ne;
  __syncthreads();
  for(int e = beg + t; e < end; e += 512){
    unsigned int p = ebuf[e];
    int pos = atomicAdd(&cur[p >> 17], 1);
    csr[pos] = (int)(p & 0x1FFFFu);
  }
}

// ---------------- fused prep: wc0 | wc1 | cast_x ----------------
// blocks [0,128): wc0, [128,256): wc1, [256,...): cast_x
__global__ void k_prep(const float* emb, const int* n_id, unsigned short* A0,
                       const float* Wl0, const float* Wr0, unsigned short* wc0,
                       const float* Wl1, const float* Wr1, unsigned short* wc1,
                       int n){
  int b = blockIdx.x;
  if(b < 256){
    const float* Wl = (b < 128) ? Wl0 : Wl1;
    const float* Wr = (b < 128) ? Wr0 : Wr1;
    unsigned short* wc = (b < 128) ? wc0 : wc1;
    int i = (b & 127)*256 + threadIdx.x;
    int nn = i >> 8, k = i & 255;
    float v = (k<128) ? Wl[nn*128 + k] : Wr[nn*128 + k - 128];
    wc[i] = f2bf(v);
  } else {
    int gid = (b-256)*256 + threadIdx.x;
    int row = gid >> 5, c4 = (gid & 31) * 4;
    if(row >= n) return;
    float4 v = *(const float4*)&emb[(long)n_id[row]*128 + c4];
    ushort4 o;
    o.x = f2bf(v.x); o.y = f2bf(v.y); o.z = f2bf(v.z); o.w = f2bf(v.w);
    *(ushort4*)&A0[(long)row*256 + 128 + c4] = o;
  }
}

// ---------------- mean aggregation: one wave per node, 4 rows per load instr ----------------
// lane = (g, gl): group g in 0..3 reads row csr[e+g], bytes gl*16..+16 of the x-half.
// One instruction = 1KB over 4 edges; a 16-edge node issues as 4 back-to-back loads.
__device__ __forceinline__ void do_quad(const char* Xb, const int* csr,
                                        int ebase, int last, int g, int gl,
                                        f32x2& a0, f32x2& a1, f32x2& a2, f32x2& a3){
  int i0 = ebase   > last ? last : ebase;      // uniform -> SALU + s_load
  int i1 = ebase+1 > last ? last : ebase+1;
  int i2 = ebase+2 > last ? last : ebase+2;
  int i3 = ebase+3 > last ? last : ebase+3;
  int c0 = csr[i0], c1 = csr[i1], c2 = csr[i2], c3 = csr[i3];
  int cg = g==0 ? c0 : g==1 ? c1 : g==2 ? c2 : c3;
  float m = (ebase + g <= last) ? 1.f : 0.f;
  const uint4 v = *(const uint4*)(Xb + (long)cg*512 + gl*16);
  accfma(a0, v.x, m); accfma(a1, v.y, m); accfma(a2, v.z, m); accfma(a3, v.w, m);
}

__global__ void k_agg(const unsigned short* X, unsigned short* Mout,
                      const int* row_off, const int* csr, int n){
  int w = __builtin_amdgcn_readfirstlane((int)((blockIdx.x*blockDim.x + threadIdx.x) >> 6));
  int lane = threadIdx.x & 63;
  int g = lane >> 4, gl = lane & 15;
  if(w >= n) return;
  int beg = row_off[w], end = row_off[w+1];
  int deg = end - beg;
  if(deg == 0){
    if(g == 0) *(uint4*)((char*)Mout + (long)w*512 + gl*16) = (uint4){0,0,0,0};
    return;
  }
  const char* Xb = (const char*)X + 256;     // x-half of the 512B row
  f32x2 a0={0.f,0.f}, a1={0.f,0.f}, a2={0.f,0.f}, a3={0.f,0.f};
  int last = end - 1;
  for(int e = beg; e < end; e += 16){
    do_quad(Xb, csr, e,    last, g, gl, a0, a1, a2, a3);
    do_quad(Xb, csr, e+4,  last, g, gl, a0, a1, a2, a3);
    do_quad(Xb, csr, e+8,  last, g, gl, a0, a1, a2, a3);
    do_quad(Xb, csr, e+12, last, g, gl, a0, a1, a2, a3);
  }
  // reduce across the 4 groups (lane bits 4,5)
#pragma unroll
  for(int off=16; off<=32; off<<=1){
    a0[0] += __shfl_xor(a0[0], off); a0[1] += __shfl_xor(a0[1], off);
    a1[0] += __shfl_xor(a1[0], off); a1[1] += __shfl_xor(a1[1], off);
    a2[0] += __shfl_xor(a2[0], off); a2[1] += __shfl_xor(a2[1], off);
    a3[0] += __shfl_xor(a3[0], off); a3[1] += __shfl_xor(a3[1], off);
  }
  float inv = 1.0f/(float)deg;
  unsigned int o0 = ((unsigned)f2bf(a0[1]*inv) << 16) | f2bf(a0[0]*inv);
  unsigned int o1 = ((unsigned)f2bf(a1[1]*inv) << 16) | f2bf(a1[0]*inv);
  unsigned int o2 = ((unsigned)f2bf(a2[1]*inv) << 16) | f2bf(a2[0]*inv);
  unsigned int o3 = ((unsigned)f2bf(a3[1]*inv) << 16) | f2bf(a3[0]*inv);
  if(g == 0) *(uint4*)((char*)Mout + (long)w*512 + gl*16) = (uint4){o0,o1,o2,o3};
}

// ---------------- GEMM: C[M,128] = A[M,256] @ Wcat^T + bias ----------------
// block = 256 thr = 4 waves; 256 rows per block (4 row-tiles of 64), W staged once.
template<int RELU, int OUTSTRIDE, int OUTOFF>
__global__ __launch_bounds__(256,2) void k_gemm(const unsigned short* A,
                                                const unsigned short* wc,
                                                const float* bias,
                                                unsigned short* out, int nrows){
  __shared__ unsigned short Wl[32768];   // 128 rows x 256 cols bf16 = 64KB
  int tid = threadIdx.x;
  // stage W into LDS with st-swizzle: byte ^= (row&7)<<4
  for(int it=0; it<16; ++it){
    int idx  = it*256 + tid;       // 16B chunk id, 4096 total
    int byte = idx*16;
    int row  = byte >> 9;
    int swz  = byte ^ ((row & 7) << 4);
    *(uint4*)((char*)Wl + swz) = *(const uint4*)((const char*)wc + byte);
  }
  __syncthreads();

  int lane = tid & 63, wv = tid >> 6;
  // hoist bias (per nf fragment, col = nf*16 + (lane&15))
  float bs[8];
#pragma unroll
  for(int nf=0; nf<8; ++nf) bs[nf] = bias[nf*16 + (lane & 15)];

  for(int t=0; t<4; ++t){
    int rowA = blockIdx.x*256 + t*64 + wv*16 + (lane & 15);
    int rcl  = rowA < nrows ? rowA : nrows-1;
    const char* Ab = (const char*)(A + (long)rcl*256) + ((lane>>4)*16);
    bf16x8 a[8];
#pragma unroll
    for(int k=0;k<8;++k) a[k] = *(const bf16x8*)(Ab + k*64);

    f32x4 acc[8];
#pragma unroll
    for(int i=0;i<8;++i) acc[i] = (f32x4){0.f,0.f,0.f,0.f};

#pragma unroll
    for(int nf=0; nf<8; ++nf){
      int rw = nf*16 + (lane & 15);
#pragma unroll
      for(int k=0;k<8;++k){
        int byte = (rw*512 + k*64 + (lane>>4)*16) ^ ((rw & 7) << 4);
        bf16x8 b = *(const bf16x8*)((const char*)Wl + byte);
        acc[nf] = __builtin_amdgcn_mfma_f32_16x16x32_bf16(a[k], b, acc[nf], 0, 0, 0);
      }
    }

    int rbase = blockIdx.x*256 + t*64 + wv*16 + (lane>>4)*4;
#pragma unroll
    for(int nf=0; nf<8; ++nf){
      int col = nf*16 + (lane & 15);
#pragma unroll
      for(int r=0;r<4;++r){
        int row = rbase + r;
        if(row < nrows){
          float v = acc[nf][r] + bs[nf];
          if(RELU) v = v > 0.f ? v : 0.f;
          out[(long)row*OUTSTRIDE + OUTOFF + col] = f2bf(v);
        }
      }
    }
  }
}

// ---------------- edge-label dot: 4 pairs per wave, 16 lanes x 16B per row ----------------
__global__ void k_dot(const unsigned short* z, const int* s, const int* d,
                      float* out, int nl){
  int wv = (blockIdx.x*256 + threadIdx.x) >> 6;   // wave id
  int lane = threadIdx.x & 63;
  int g = lane >> 4;                               // group 0..3 (one pair each)
  int gl = lane & 15;                              // lane within group
  int pi = wv*4 + g;
  float acc = 0.f;
  if(pi < nl){
    int si = s[pi], di = d[pi];
    bf16x8 va = *(const bf16x8*)&z[(long)si*128 + gl*8];
    bf16x8 vb = *(const bf16x8*)&z[(long)di*128 + gl*8];
#pragma unroll
    for(int i=0;i<8;++i)
      acc += bf2f((unsigned short)va[i]) * bf2f((unsigned short)vb[i]);
#pragma unroll
    for(int off=1; off<16; off<<=1)
      acc += __shfl_xor(acc, off, 16);
    if(gl==0) out[pi] = acc;
  }
}

extern "C" void kernel_launch(void* const* d_in, const int* in_sizes, int n_in,
                              void* d_out, int out_size, void* d_ws, size_t ws_size,
                              hipStream_t stream){
  const int N  = in_sizes[0];
  const int NE = in_sizes[1] / 2;
  const int NL = in_sizes[2] / 2;
  const int*   n_id = (const int*)d_in[0];
  const int*   src  = (const int*)d_in[1];
  const int*   dst  = src + NE;
  const int*   ls   = (const int*)d_in[2];
  const int*   ld   = ls + NL;
  const float* emb  = (const float*)d_in[3];
  const float* Wl0  = (const float*)d_in[4];
  const float* bl0  = (const float*)d_in[5];
  const float* Wr0  = (const float*)d_in[6];
  const float* Wl1  = (const float*)d_in[7];
  const float* bl1  = (const float*)d_in[8];
  const float* Wr1  = (const float*)d_in[9];
  float* out = (float*)d_out;

  char* ws = (char*)d_ws;
  size_t off = 0;
  auto alloc = [&](size_t bytes)->char*{
    char* p = ws + off;
    off = (off + bytes + 255) & ~(size_t)255;
    return p;
  };
  unsigned short* A0   = (unsigned short*)alloc((size_t)N*256*2);   // [mean0|x]
  unsigned short* A1   = (unsigned short*)alloc((size_t)N*256*2);   // [mean1|h]
  int* row_off         = (int*)alloc((size_t)(N+1)*4);
  int* csr             = (int*)alloc((size_t)NE*4);
  int* gcount          = (int*)alloc(MAXBKT*4);
  int* gbase           = (int*)alloc(MAXBKT*4);
  int* gcursor         = (int*)alloc(MAXBKT*4);
  unsigned short* wc0  = (unsigned short*)alloc(128*256*2);
  unsigned short* wc1  = (unsigned short*)alloc(128*256*2);
  unsigned int* ebuf   = (unsigned int*)A1;  // 6.4MB overlay, dead before gemm0
  unsigned short* Z    = A0;                 // reuse A0 for z [N][128]

  const int NBK = (N + BKT_RANGE - 1) >> BKT_SHIFT;   // <= 256
  const int NCH = (NE + 4095) / 4096;

  hipMemsetAsync(gcount, 0, NBK*4, stream);
  hipLaunchKernelGGL(k_bcount,   dim3(NCH),          dim3(256), 0, stream, dst, gcount, NE, NBK);
  hipLaunchKernelGGL(k_bscan,    dim3(1),            dim3(256), 0, stream, gcount, gbase, gcursor, NBK);
  hipLaunchKernelGGL(k_bscatter, dim3(NCH),          dim3(256), 0, stream, src, dst, gcursor, ebuf, NE, NBK);
  hipLaunchKernelGGL(k_bsort,    dim3(NBK),          dim3(512), 0, stream, ebuf, gbase, gcursor, csr, row_off, N, NE, NBK);
  hipLaunchKernelGGL(k_prep,     dim3(256 + (N*32+255)/256), dim3(256), 0, stream,
                     emb, n_id, A0, Wl0, Wr0, wc0, Wl1, Wr1, wc1, N);
  // layer 0
  hipLaunchKernelGGL(k_agg,      dim3((N*64+255)/256),dim3(256), 0, stream, A0, A0, row_off, csr, N);
  hipLaunchKernelGGL((k_gemm<1,256,128>), dim3((N+255)/256), dim3(256), 0, stream, A0, wc0, bl0, A1, N);
  // layer 1
  hipLaunchKernelGGL(k_agg,      dim3((N*64+255)/256),dim3(256), 0, stream, A1, A1, row_off, csr, N);
  hipLaunchKernelGGL((k_gemm<0,128,0>),   dim3((N+255)/256), dim3(256), 0, stream, A1, wc1, bl1, Z, N);
  // edge-label dots
  hipLaunchKernelGGL(k_dot,      dim3((NL+15)/16),   dim3(256), 0, stream, Z, ls, ld, out, NL);
}

// Round 7
// 260.379 us; speedup vs baseline: 1.0486x; 1.0486x over previous
//
#include <hip/hip_runtime.h>
#include <hip/hip_bf16.h>

typedef short bf16x8 __attribute__((ext_vector_type(8)));
typedef float f32x4 __attribute__((ext_vector_type(4)));
typedef float f32x2 __attribute__((ext_vector_type(2)));

#define BKT_SHIFT 9
#define BKT_RANGE 512          // nodes per bucket
#define MAXBKT 256             // N <= 131072 (src packs in 17 bits)

__device__ __forceinline__ float bf2f(unsigned short u){
  union { unsigned int i; float f; } v; v.i = ((unsigned int)u)<<16; return v.f;
}
__device__ __forceinline__ unsigned short f2bf(float f){
  union { float f; unsigned int i; } v; v.f = f;
  unsigned int i = v.i;
  return (unsigned short)((i + 0x7fffu + ((i>>16)&1u)) >> 16);  // RNE
}
// unpack 2 packed bf16 into float2 {lo, hi}: 2 VALU (shl, and)
__device__ __forceinline__ f32x2 up2(unsigned int v){
  union { unsigned int i; float f; } lo, hi;
  lo.i = v << 16; hi.i = v & 0xffff0000u;
  return (f32x2){lo.f, hi.f};
}

// ---------------- bucket-sort CSR build ----------------
// B1: per-block LDS histogram of dst-buckets -> global bucket counts
__global__ void k_bcount(const int* dst, int* gcount, int ne, int nbk){
  __shared__ int cnt[MAXBKT];
  int tid = threadIdx.x;
  if(tid < nbk) cnt[tid] = 0;
  __syncthreads();
  int base = blockIdx.x * 4096;
#pragma unroll
  for(int i=0;i<16;++i){
    int e = base + i*256 + tid;
    if(e < ne) atomicAdd(&cnt[dst[e] >> BKT_SHIFT], 1);
  }
  __syncthreads();
  if(tid < nbk && cnt[tid] > 0) atomicAdd(&gcount[tid], cnt[tid]);
}

// B3 (+fused prep): blocks [0,nch): scatter packed (src | dloc<<17) into ebuf;
// blocks [nch, nch+256): wcat; blocks [nch+256, ...): cast_x.
__global__ void k_bscatter_prep(const int* src, const int* dst, const int* gcount,
                                int* gcur0, unsigned int* ebuf, int ne, int nbk, int nch,
                                const float* emb, const int* n_id, unsigned short* A0,
                                const float* Wl0, const float* Wr0, unsigned short* wc0,
                                const float* Wl1, const float* Wr1, unsigned short* wc1,
                                int n){
  int b = blockIdx.x;
  int tid = threadIdx.x;
  if(b >= nch){
    int pb = b - nch;
    if(pb < 256){
      const float* Wl = (pb < 128) ? Wl0 : Wl1;
      const float* Wr = (pb < 128) ? Wr0 : Wr1;
      unsigned short* wc = (pb < 128) ? wc0 : wc1;
      int i = (pb & 127)*256 + tid;
      int nn = i >> 8, k = i & 255;
      float v = (k<128) ? Wl[nn*128 + k] : Wr[nn*128 + k - 128];
      wc[i] = f2bf(v);
    } else {
      int gid = (pb-256)*256 + tid;
      int row = gid >> 5, c4 = (gid & 31) * 4;
      if(row >= n) return;
      float4 v = *(const float4*)&emb[(long)n_id[row]*128 + c4];
      ushort4 o;
      o.x = f2bf(v.x); o.y = f2bf(v.y); o.z = f2bf(v.z); o.w = f2bf(v.w);
      *(ushort4*)&A0[(long)row*256 + 128 + c4] = o;
    }
    return;
  }
  __shared__ int cnt[MAXBKT];
  __shared__ int runbase[MAXBKT];
  __shared__ int sg[MAXBKT];
  cnt[tid] = 0;
  sg[tid] = (tid < nbk) ? gcount[tid] : 0;
  __syncthreads();
  int base = b * 4096;
  int pk[16], bk[16], re[16];
#pragma unroll
  for(int i=0;i<16;++i){
    int e = base + i*256 + tid;
    if(e < ne){
      int d = dst[e];
      bk[i] = d >> BKT_SHIFT;
      pk[i] = (unsigned)src[e] | ((unsigned)(d & (BKT_RANGE-1)) << 17);
      re[i] = atomicAdd(&cnt[bk[i]], 1);
    } else bk[i] = -1;
  }
  // local exclusive scan of gcount -> bucket base
  int myv = sg[tid];
  __syncthreads();
  for(int off=1; off<256; off<<=1){
    int a = (tid>=off) ? sg[tid-off] : 0;
    __syncthreads();
    sg[tid] += a;
    __syncthreads();
  }
  if(tid < nbk)
    runbase[tid] = (sg[tid] - myv) + (cnt[tid] ? atomicAdd(&gcur0[tid], cnt[tid]) : 0);
  __syncthreads();
#pragma unroll
  for(int i=0;i<16;++i){
    if(bk[i] >= 0) ebuf[runbase[bk[i]] + re[i]] = pk[i];
  }
}

// B4: per-bucket counting sort -> csr + row_off. grid = nbk, block = 512.
__global__ void k_bsort(const unsigned int* ebuf, const int* gcount,
                        int* csr, int* row_off, int n, int ne, int nbk){
  __shared__ int sg[MAXBKT];
  __shared__ int h[BKT_RANGE];
  __shared__ int cur[BKT_RANGE];
  __shared__ int sm[512];
  int t = threadIdx.x;
  int k = blockIdx.x;
  // local exclusive scan of gcount (threads <256 work, all sync)
  if(t < MAXBKT) sg[t] = (t < nbk) ? gcount[t] : 0;
  __syncthreads();
  for(int off=1; off<256; off<<=1){
    int a = (t>=off && t<256) ? sg[t-off] : 0;
    __syncthreads();
    if(t<256) sg[t] += a;
    __syncthreads();
  }
  int beg = sg[k] - gcount[k];
  int end = sg[k];
  int lo = k << BKT_SHIFT;
  h[t] = 0;
  __syncthreads();
  for(int e = beg + t; e < end; e += 512)
    atomicAdd(&h[ebuf[e] >> 17], 1);
  __syncthreads();
  int v = h[t];
  sm[t] = v;
  __syncthreads();
  for(int off=1; off<512; off<<=1){
    int a = (t>=off) ? sm[t-off] : 0;
    __syncthreads();
    sm[t] += a;
    __syncthreads();
  }
  int excl = beg + sm[t] - v;
  cur[t] = excl;
  if(lo + t < n) row_off[lo + t] = excl;
  if(k == nbk-1 && t == 0) row_off[n] = ne;
  __syncthreads();
  for(int e = beg + t; e < end; e += 512){
    unsigned int p = ebuf[e];
    int pos = atomicAdd(&cur[p >> 17], 1);
    csr[pos] = (int)(p & 0x1FFFFu);
  }
}

// ---------------- mean aggregation: one wave per node, scalar addressing ----------------
// w wave-uniform via readfirstlane -> csr[e] becomes s_load (dwordx8 when unrolled),
// row base in SGPRs, per-lane voffset fixed. Per-edge VALU: shl+and+pk_add only.
__global__ void k_agg(const unsigned short* X, unsigned short* Mout,
                      const int* row_off, const int* csr, int n){
  int w = __builtin_amdgcn_readfirstlane((int)((blockIdx.x*blockDim.x + threadIdx.x) >> 6));
  int lane = threadIdx.x & 63;
  if(w >= n) return;
  int beg = row_off[w], end = row_off[w+1];
  int deg = end - beg;
  f32x2 acc = {0.f, 0.f};
  const char* Xb = (const char*)X + 256;     // x-half of the 512B row
  int e = beg;
  for(; e + 8 <= end; e += 8){
    unsigned int v0 = ((const unsigned int*)(Xb + (long)csr[e  ]*512))[lane];
    unsigned int v1 = ((const unsigned int*)(Xb + (long)csr[e+1]*512))[lane];
    unsigned int v2 = ((const unsigned int*)(Xb + (long)csr[e+2]*512))[lane];
    unsigned int v3 = ((const unsigned int*)(Xb + (long)csr[e+3]*512))[lane];
    unsigned int v4 = ((const unsigned int*)(Xb + (long)csr[e+4]*512))[lane];
    unsigned int v5 = ((const unsigned int*)(Xb + (long)csr[e+5]*512))[lane];
    unsigned int v6 = ((const unsigned int*)(Xb + (long)csr[e+6]*512))[lane];
    unsigned int v7 = ((const unsigned int*)(Xb + (long)csr[e+7]*512))[lane];
    acc += up2(v0); acc += up2(v1); acc += up2(v2); acc += up2(v3);
    acc += up2(v4); acc += up2(v5); acc += up2(v6); acc += up2(v7);
  }
  for(; e + 4 <= end; e += 4){
    unsigned int v0 = ((const unsigned int*)(Xb + (long)csr[e  ]*512))[lane];
    unsigned int v1 = ((const unsigned int*)(Xb + (long)csr[e+1]*512))[lane];
    unsigned int v2 = ((const unsigned int*)(Xb + (long)csr[e+2]*512))[lane];
    unsigned int v3 = ((const unsigned int*)(Xb + (long)csr[e+3]*512))[lane];
    acc += up2(v0); acc += up2(v1); acc += up2(v2); acc += up2(v3);
  }
  for(; e < end; ++e){
    unsigned int v = ((const unsigned int*)(Xb + (long)csr[e]*512))[lane];
    acc += up2(v);
  }
  float inv = (deg>0) ? 1.0f/(float)deg : 0.f;
  float a0 = acc[0]*inv, a1 = acc[1]*inv;
  unsigned int o = ((unsigned int)f2bf(a1) << 16) | (unsigned int)f2bf(a0);
  *(unsigned int*)((char*)Mout + (long)w*512 + lane*4) = o;
}

// ---------------- GEMM: C[M,128] = A[M,256] @ Wcat^T + bias ----------------
// block = 256 thr = 4 waves; 256 rows per block (4 row-tiles of 64), W staged once.
template<int RELU, int OUTSTRIDE, int OUTOFF>
__global__ __launch_bounds__(256,2) void k_gemm(const unsigned short* A,
                                                const unsigned short* wc,
                                                const float* bias,
                                                unsigned short* out, int nrows){
  __shared__ unsigned short Wl[32768];   // 128 rows x 256 cols bf16 = 64KB
  int tid = threadIdx.x;
  // stage W into LDS with st-swizzle: byte ^= (row&7)<<4
  for(int it=0; it<16; ++it){
    int idx  = it*256 + tid;       // 16B chunk id, 4096 total
    int byte = idx*16;
    int row  = byte >> 9;
    int swz  = byte ^ ((row & 7) << 4);
    *(uint4*)((char*)Wl + swz) = *(const uint4*)((const char*)wc + byte);
  }
  __syncthreads();

  int lane = tid & 63, wv = tid >> 6;
  // hoist bias (per nf fragment, col = nf*16 + (lane&15))
  float bs[8];
#pragma unroll
  for(int nf=0; nf<8; ++nf) bs[nf] = bias[nf*16 + (lane & 15)];

  for(int t=0; t<4; ++t){
    int rowA = blockIdx.x*256 + t*64 + wv*16 + (lane & 15);
    int rcl  = rowA < nrows ? rowA : nrows-1;
    const char* Ab = (const char*)(A + (long)rcl*256) + ((lane>>4)*16);
    bf16x8 a[8];
#pragma unroll
    for(int k=0;k<8;++k) a[k] = *(const bf16x8*)(Ab + k*64);

    f32x4 acc[8];
#pragma unroll
    for(int i=0;i<8;++i) acc[i] = (f32x4){0.f,0.f,0.f,0.f};

#pragma unroll
    for(int nf=0; nf<8; ++nf){
      int rw = nf*16 + (lane & 15);
#pragma unroll
      for(int k=0;k<8;++k){
        int byte = (rw*512 + k*64 + (lane>>4)*16) ^ ((rw & 7) << 4);
        bf16x8 b = *(const bf16x8*)((const char*)Wl + byte);
        acc[nf] = __builtin_amdgcn_mfma_f32_16x16x32_bf16(a[k], b, acc[nf], 0, 0, 0);
      }
    }

    int rbase = blockIdx.x*256 + t*64 + wv*16 + (lane>>4)*4;
#pragma unroll
    for(int nf=0; nf<8; ++nf){
      int col = nf*16 + (lane & 15);
#pragma unroll
      for(int r=0;r<4;++r){
        int row = rbase + r;
        if(row < nrows){
          float v = acc[nf][r] + bs[nf];
          if(RELU) v = v > 0.f ? v : 0.f;
          out[(long)row*OUTSTRIDE + OUTOFF + col] = f2bf(v);
        }
      }
    }
  }
}

// ---------------- edge-label dot: 4 pairs per wave, 16 lanes x 16B per row ----------------
__global__ void k_dot(const unsigned short* z, const int* s, const int* d,
                      float* out, int nl){
  int wv = (blockIdx.x*256 + threadIdx.x) >> 6;   // wave id
  int lane = threadIdx.x & 63;
  int g = lane >> 4;                               // group 0..3 (one pair each)
  int gl = lane & 15;                              // lane within group
  int pi = wv*4 + g;
  float acc = 0.f;
  if(pi < nl){
    int si = s[pi], di = d[pi];
    bf16x8 va = *(const bf16x8*)&z[(long)si*128 + gl*8];
    bf16x8 vb = *(const bf16x8*)&z[(long)di*128 + gl*8];
#pragma unroll
    for(int i=0;i<8;++i)
      acc += bf2f((unsigned short)va[i]) * bf2f((unsigned short)vb[i]);
#pragma unroll
    for(int off=1; off<16; off<<=1)
      acc += __shfl_xor(acc, off, 16);
    if(gl==0) out[pi] = acc;
  }
}

extern "C" void kernel_launch(void* const* d_in, const int* in_sizes, int n_in,
                              void* d_out, int out_size, void* d_ws, size_t ws_size,
                              hipStream_t stream){
  const int N  = in_sizes[0];
  const int NE = in_sizes[1] / 2;
  const int NL = in_sizes[2] / 2;
  const int*   n_id = (const int*)d_in[0];
  const int*   src  = (const int*)d_in[1];
  const int*   dst  = src + NE;
  const int*   ls   = (const int*)d_in[2];
  const int*   ld   = ls + NL;
  const float* emb  = (const float*)d_in[3];
  const float* Wl0  = (const float*)d_in[4];
  const float* bl0  = (const float*)d_in[5];
  const float* Wr0  = (const float*)d_in[6];
  const float* Wl1  = (const float*)d_in[7];
  const float* bl1  = (const float*)d_in[8];
  const float* Wr1  = (const float*)d_in[9];
  float* out = (float*)d_out;

  char* ws = (char*)d_ws;
  size_t off = 0;
  auto alloc = [&](size_t bytes)->char*{
    char* p = ws + off;
    off = (off + bytes + 255) & ~(size_t)255;
    return p;
  };
  unsigned short* A0   = (unsigned short*)alloc((size_t)N*256*2);   // [mean0|x]
  unsigned short* A1   = (unsigned short*)alloc((size_t)N*256*2);   // [mean1|h]
  int* row_off         = (int*)alloc((size_t)(N+1)*4);
  int* csr             = (int*)alloc((size_t)NE*4);
  int* gcount          = (int*)alloc(MAXBKT*4*2);   // gcount | gcur0
  int* gcur0           = gcount + MAXBKT;
  unsigned short* wc0  = (unsigned short*)alloc(128*256*2);
  unsigned short* wc1  = (unsigned short*)alloc(128*256*2);
  unsigned int* ebuf   = (unsigned int*)A1;  // 6.4MB overlay, dead before gemm0
  unsigned short* Z    = A0;                 // reuse A0 for z [N][128]

  const int NBK = (N + BKT_RANGE - 1) >> BKT_SHIFT;   // <= 256
  const int NCH = (NE + 4095) / 4096;

  hipMemsetAsync(gcount, 0, MAXBKT*4*2, stream);
  hipLaunchKernelGGL(k_bcount, dim3(NCH), dim3(256), 0, stream, dst, gcount, NE, NBK);
  hipLaunchKernelGGL(k_bscatter_prep, dim3(NCH + 256 + (N*32+255)/256), dim3(256), 0, stream,
                     src, dst, gcount, gcur0, ebuf, NE, NBK, NCH,
                     emb, n_id, A0, Wl0, Wr0, wc0, Wl1, Wr1, wc1, N);
  hipLaunchKernelGGL(k_bsort, dim3(NBK), dim3(512), 0, stream,
                     ebuf, gcount, csr, row_off, N, NE, NBK);
  // layer 0
  hipLaunchKernelGGL(k_agg, dim3((N*64+255)/256), dim3(256), 0, stream, A0, A0, row_off, csr, N);
  hipLaunchKernelGGL((k_gemm<1,256,128>), dim3((N+255)/256), dim3(256), 0, stream, A0, wc0, bl0, A1, N);
  // layer 1
  hipLaunchKernelGGL(k_agg, dim3((N*64+255)/256), dim3(256), 0, stream, A1, A1, row_off, csr, N);
  hipLaunchKernelGGL((k_gemm<0,128,0>), dim3((N+255)/256), dim3(256), 0, stream, A1, wc1, bl1, Z, N);
  // edge-label dots
  hipLaunchKernelGGL(k_dot, dim3((NL+15)/16), dim3(256), 0, stream, Z, ls, ld, out, NL);
}